// Round 7
// baseline (10616.350 us; speedup 1.0000x reference)
//
#include <hip/hip_runtime.h>

typedef unsigned int u32;
typedef unsigned char u8;
typedef u32 u32x4 __attribute__((ext_vector_type(4)));

#define TSTART 48
#define TEND   49
#define NEGV  -10000.0f

// ---- workspace byte offsets ----
#define O_XG     0ull            // 4096*256*4   = 4,194,304 (x gathered f16x2, k 250->256)
#define O_WIHF   4194304ull      // 800*256*4    = 819,200
#define O_WIHB   5013504ull      // 819,200
#define O_WHHF   5832704ull      // 1024 chunks * 92 dwords * 4 = 376,832 (per-thread packed)
#define O_WHHB   6209536ull      // 376,832
#define O_BSF    6586368ull      // 3,200
#define O_BSB    6589568ull      // 3,200
#define O_LWP    6592768ull      // 50*200*4 = 40,000 (linear_w packed f16 pairs)
#define O_XF     6632768ull      // 4096*800*4 = 13,107,200
#define O_XB     19739968ull     // 13,107,200
#define O_HT     32847168ull     // 200 rows * 4096 * 4 = 3,276,800 (h pairs f16x2, [pair][seq])
#define O_FEATS  36123968ull     // 4096*50*4 = 819,200
#define O_BP     36943168ull     // 204,800
#define O_FMAP   37147968ull     // 3,200
#define O_BTAG   37151168ull     // 256
#define O_SCAL   37151424ull     // 64

typedef _Float16 h2 __attribute__((ext_vector_type(2)));

__device__ __forceinline__ float fdot2(u32 a, u32 b, float c) {
#if defined(__HIP_DEVICE_COMPILE__) && __has_builtin(__builtin_amdgcn_fdot2)
    return __builtin_amdgcn_fdot2(__builtin_bit_cast(h2, a), __builtin_bit_cast(h2, b), c, false);
#else
    float d;
    asm("v_dot2_f32_f16 %0, %1, %2, %3" : "=v"(d) : "v"(a), "v"(b), "v"(c));
    return d;
#endif
}

__device__ __forceinline__ u32 pack2(float a, float b) {
    u32 lo = __builtin_bit_cast(unsigned short, (_Float16)a);
    u32 hi = __builtin_bit_cast(unsigned short, (_Float16)b);
    return lo | (hi << 16);
}

__device__ __forceinline__ float sigf(float x) { return 1.f / (1.f + __expf(-x)); }
__device__ __forceinline__ float tanhf_(float x) { return 2.f / (1.f + __expf(-2.f * x)) - 1.f; }

// element ranges in k_prep's flat index space (dword elements)
#define PA_END   94208      // whf packed (1024 chunks * 92)
#define PB_END   188416     // whb packed
#define PC_END   393216     // wihf
#define PD_END   598016     // wihb
#define PE_END   1646592    // xg
#define PF_END   1656592    // lwpack
#define PG_END   1657392    // bsf
#define PH_END   1658192    // bsb

// whh per-thread packed layout: chunk = thread id t in [0,1024) = rgrp*8+ks.
// chunk = 92 dwords: off<84: q=off>>2,e=off&3,c4=q/7,m=q%7 -> row=rgrp*7+m, kd=ks*13+c4*4+e
//         off in [84,91): m=off-84, kd=ks*13+12 ; off=91: zero pad
__global__ __launch_bounds__(256) void k_prep(
    const int* __restrict__ ids, const float* __restrict__ emb,
    const float* __restrict__ wihf, const float* __restrict__ wihb,
    const float* __restrict__ whhf, const float* __restrict__ whhb,
    const float* __restrict__ bihf, const float* __restrict__ bhhf,
    const float* __restrict__ bihb, const float* __restrict__ bhhb,
    const float* __restrict__ lw,
    u32* __restrict__ xg, u32* __restrict__ wif16, u32* __restrict__ wib16,
    u32* __restrict__ whf16, u32* __restrict__ whb16, u32* __restrict__ lwp,
    float* __restrict__ bsf, float* __restrict__ bsb)
{
    int idx = blockIdx.x * 256 + threadIdx.x;
    if (idx < PB_END) {                               // packed whh (both dirs)
        int dirb = (idx >= PA_END);
        int i = idx - (dirb ? PA_END : 0);
        const float* whh = dirb ? whhb : whhf;
        u32* dst = dirb ? whb16 : whf16;
        int chunk = i / 92, off = i % 92;
        int rgrp = chunk >> 3, ks = chunk & 7;
        u32 v = 0;
        if (off < 91) {
            int m, kd;
            if (off < 84) { int q = off >> 2, e = off & 3; int c4 = q / 7; m = q % 7; kd = ks * 13 + c4 * 4 + e; }
            else          { m = off - 84; kd = ks * 13 + 12; }
            int row = rgrp * 7 + m;
            if (row < 800 && kd < 100) v = pack2(whh[row * 200 + 2 * kd], whh[row * 200 + 2 * kd + 1]);
        }
        dst[i] = v;
    } else if (idx < PD_END) {                        // wih: [800][256]
        int dirb = (idx >= PC_END);
        int i = idx - (dirb ? PC_END : PB_END);
        const float* wih = dirb ? wihb : wihf;
        u32* dst = dirb ? wib16 : wif16;
        int r = i >> 8, d = i & 255;
        dst[i] = (d < 250) ? pack2(wih[r * 500 + 2 * d], wih[r * 500 + 2 * d + 1]) : 0u;
    } else if (idx < PE_END) {                        // xg: [4096][256]
        int i = idx - PD_END; int s = i >> 8, d = i & 255;
        long id = ids[s];
        xg[i] = (d < 250) ? pack2(emb[id * 500 + 2 * d], emb[id * 500 + 2 * d + 1]) : 0u;
    } else if (idx < PF_END) {                        // lwpack [50][200]
        int i = idx - PE_END; int tag = i / 200, u = i % 200;
        lwp[i] = pack2(lw[tag * 400 + 2 * u], lw[tag * 400 + 2 * u + 1]);
    } else if (idx < PG_END) {
        int j = idx - PF_END; bsf[j] = bihf[j] + bhhf[j];
    } else if (idx < PH_END) {
        int j = idx - PG_END; bsb[j] = bihb[j] + bhhb[j];
    }
}

// =============== K1: input GEMM  xp[s][j] = dot(x[s or rev], w_ih[j]) + bias ===============
__global__ __launch_bounds__(256, 2) void k_gemm(
    const u32* __restrict__ xg, const u32* __restrict__ wf, const u32* __restrict__ wb,
    const float* __restrict__ bsf, const float* __restrict__ bsb,
    float* __restrict__ xf, float* __restrict__ xb)
{
    int z = blockIdx.z;
    const u32* W = z ? wb : wf;
    const float* bs = z ? bsb : bsf;
    float* out = z ? xb : xf;
    int m0 = blockIdx.x * 256, n0 = blockIdx.y * 128;
    int t = threadIdx.x;

    __shared__ u32 As[16][256];
    __shared__ u32 Bs[16][128];

    float acc[16][8];
#pragma unroll
    for (int m = 0; m < 16; m++)
#pragma unroll
        for (int n = 0; n < 8; n++) acc[m][n] = 0.f;

    int arow = m0 + t; if (z) arow = 4095 - arow;
    const u32* aptr = xg + (size_t)arow * 256;
    int bj = n0 + (t >> 1);
    int ko = (t & 1) * 8;
    const u32* bptr = W + (size_t)bj * 256 + ko;

    int ry = t >> 4, cx = t & 15;

    for (int kc = 0; kc < 16; ++kc) {
        int kd = kc * 16;
        uint4 a0 = *(const uint4*)(aptr + kd);
        uint4 a1 = *(const uint4*)(aptr + kd + 4);
        uint4 a2 = *(const uint4*)(aptr + kd + 8);
        uint4 a3 = *(const uint4*)(aptr + kd + 12);
        uint4 bv0 = {0,0,0,0}, bv1 = {0,0,0,0};
        if (bj < 800) { bv0 = *(const uint4*)(bptr + kd); bv1 = *(const uint4*)(bptr + kd + 4); }
        __syncthreads();
        u32 ad[16] = {a0.x,a0.y,a0.z,a0.w, a1.x,a1.y,a1.z,a1.w,
                      a2.x,a2.y,a2.z,a2.w, a3.x,a3.y,a3.z,a3.w};
#pragma unroll
        for (int i = 0; i < 16; i++) As[i][t] = ad[i];
        u32 bd[8] = {bv0.x,bv0.y,bv0.z,bv0.w, bv1.x,bv1.y,bv1.z,bv1.w};
#pragma unroll
        for (int i = 0; i < 8; i++) Bs[ko + i][t >> 1] = bd[i];
        __syncthreads();
#pragma unroll
        for (int d = 0; d < 16; ++d) {
            const u32* ar = &As[d][ry * 16];
            uint4 x0 = *(const uint4*)(ar);
            uint4 x1 = *(const uint4*)(ar + 4);
            uint4 x2 = *(const uint4*)(ar + 8);
            uint4 x3 = *(const uint4*)(ar + 12);
            const u32* br = &Bs[d][cx * 8];
            uint4 y0 = *(const uint4*)(br);
            uint4 y1 = *(const uint4*)(br + 4);
            u32 am[16] = {x0.x,x0.y,x0.z,x0.w, x1.x,x1.y,x1.z,x1.w,
                          x2.x,x2.y,x2.z,x2.w, x3.x,x3.y,x3.z,x3.w};
            u32 bn[8] = {y0.x,y0.y,y0.z,y0.w, y1.x,y1.y,y1.z,y1.w};
#pragma unroll
            for (int m = 0; m < 16; m++)
#pragma unroll
                for (int n = 0; n < 8; n++)
                    acc[m][n] = fdot2(am[m], bn[n], acc[m][n]);
        }
    }
    int col = n0 + cx * 8;
    if (col < 800) {
        float4 bi0 = *(const float4*)(bs + col);
        float4 bi1 = *(const float4*)(bs + col + 4);
#pragma unroll
        for (int m = 0; m < 16; m++) {
            size_t ro = (size_t)(m0 + ry * 16 + m) * 800 + col;
            float4 o0 = {acc[m][0]+bi0.x, acc[m][1]+bi0.y, acc[m][2]+bi0.z, acc[m][3]+bi0.w};
            float4 o1 = {acc[m][4]+bi1.x, acc[m][5]+bi1.y, acc[m][6]+bi1.z, acc[m][7]+bi1.w};
            *(float4*)(out + ro) = o0;
            *(float4*)(out + ro + 4) = o1;
        }
    }
}

// =============== K2: LSTM recurrence. 1024 threads: t = rgrp*8+ks ===============
// rgrp in [0,128): rows rgrp*7..+6 (padded 896); ks in [0,8): k-dwords ks*13..+12 of 100.
// Weights (92 dwords/thread) via volatile asm global_load_dwordx4 + in-asm vmcnt(0)
// (opaque -> non-sinkable; complete-at-def -> spill-safe).
// KEY FIX vs rounds 4/6 (VGPR=64, all W spilled): the backend budgets VGPRs by its
// ACHIEVABLE-OCCUPANCY estimate (2 blocks/CU @7.5KB LDS -> 8 waves/EU -> 64 VGPR).
// An 84 KB static LDS anchor forces 1 block/CU -> 4 waves/EU ceiling -> 128-VGPR
// budget with nothing to gain by crushing -> weights stay resident. (gfx950 allows
// >64KB static LDS; occupancy is irrelevant here: 2 blocks on 256 CUs.)

#define GLOADW(dst, ptr, off) \
    asm volatile("global_load_dwordx4 %0, %1, off offset:" #off "\n\t" \
                 "s_waitcnt vmcnt(0)" \
                 : "=&v"(dst) : "v"(ptr) : "memory")

#define DOTQ(Wv, A) \
    A = fdot2(Wv.x, hb.x, A); A = fdot2(Wv.y, hb.y, A); \
    A = fdot2(Wv.z, hb.z, A); A = fdot2(Wv.w, hb.w, A);

#define DOT_BLOCK(hboff, Wa, Wb, Wc, Wd, We, Wf, Wg) { \
    u32x4 hb = *(const u32x4*)(hbase + (hboff)); \
    DOTQ(Wa, acc0) DOTQ(Wb, acc1) DOTQ(Wc, acc2) DOTQ(Wd, acc3) \
    DOTQ(We, acc4) DOTQ(Wf, acc5) DOTQ(Wg, acc6) }

#define REDUCE(A) A += __shfl_xor(A, 1); A += __shfl_xor(A, 2); A += __shfl_xor(A, 4);

__global__ __launch_bounds__(1024, 4)
void k_lstm(
    const u32* __restrict__ whf, const u32* __restrict__ whb,
    const float* __restrict__ xf, const float* __restrict__ xb,
    const float* __restrict__ h0, const float* __restrict__ c0,
    u32* __restrict__ hallT)
{
    int dir = blockIdx.x, t = threadIdx.x;
    const u32* Wh = dir ? whb : whf;
    const float* xp = dir ? xb : xf;
    int ks = t & 7, rgrp = t >> 3, r0 = rgrp * 7;

    // ---- LDS occupancy anchor: 76800 B + live buffers = ~84 KB -> 1 block/CU ----
    __shared__ u32 anchor[19200];
    __shared__ __align__(16) u32 hsh[160];   // 8 slices * 20 dwords (13 used)
    __shared__ float gsh[896];
    __shared__ u32 hstage[800];              // [8 steps][100 pairs]

    {   // keep anchor alive (rule #17): opaque index, asm-consumed read
        u32 ai;
        asm volatile("v_mov_b32 %0, %1" : "=v"(ai) : "v"((u32)t));
        anchor[ai] = ai;
        u32 zz = anchor[ai ^ 1];
        asm volatile("" :: "v"(zz));
    }

    const u32* wptr = Wh + (size_t)t * 92;
    u32x4 W0,W1,W2,W3,W4,W5,W6,W7,W8,W9,W10,W11,W12,W13,W14,W15,W16,W17,W18,W19,W20,W21,W22;
    GLOADW(W0,  wptr,   0); GLOADW(W1,  wptr,  16); GLOADW(W2,  wptr,  32);
    GLOADW(W3,  wptr,  48); GLOADW(W4,  wptr,  64); GLOADW(W5,  wptr,  80);
    GLOADW(W6,  wptr,  96); GLOADW(W7,  wptr, 112); GLOADW(W8,  wptr, 128);
    GLOADW(W9,  wptr, 144); GLOADW(W10, wptr, 160); GLOADW(W11, wptr, 176);
    GLOADW(W12, wptr, 192); GLOADW(W13, wptr, 208); GLOADW(W14, wptr, 224);
    GLOADW(W15, wptr, 240); GLOADW(W16, wptr, 256); GLOADW(W17, wptr, 272);
    GLOADW(W18, wptr, 288); GLOADW(W19, wptr, 304); GLOADW(W20, wptr, 320);
    GLOADW(W21, wptr, 336); GLOADW(W22, wptr, 352);

    if (t < 160) hsh[t] = 0u;
    __syncthreads();

    float cst = 0.f;
    int haddr = 0;
    if (t < 200) {
        cst = c0[dir * 200 + t];
        int u = t >> 1;
        haddr = (u / 13) * 20 + (u % 13);
        if (!(t & 1)) hsh[haddr] = pack2(h0[dir * 200 + t], h0[dir * 200 + t + 1]);
    }
    __syncthreads();

    const u32* hbase = hsh + ks * 20;

    for (int s = 0; s < 4096; ++s) {
        // x loads for THIS step issued early: latency hides under dot work,
        // so barrier A's vmcnt drain is free.
        float xr0 = 0.f, xr1 = 0.f, xr2 = 0.f, xr3 = 0.f;
        if (t < 200) {
            size_t xo = (size_t)s * 800 + t;
            xr0 = xp[xo]; xr1 = xp[xo + 200]; xr2 = xp[xo + 400]; xr3 = xp[xo + 600];
        }
        // flush previous 8-step h batch from LDS stage (store-ack drains with x loads)
        if ((s & 7) == 0 && s && t < 100) {
            int s0 = s - 8;
            u32 a0 = hstage[t],       a1 = hstage[100 + t], a2 = hstage[200 + t], a3 = hstage[300 + t];
            u32 a4 = hstage[400 + t], a5 = hstage[500 + t], a6 = hstage[600 + t], a7 = hstage[700 + t];
            uint4* dst;
            uint4 v0, v1;
            if (dir == 0) {
                dst = (uint4*)(hallT + (size_t)t * 4096 + s0);
                v0 = (uint4){a0, a1, a2, a3}; v1 = (uint4){a4, a5, a6, a7};
            } else {
                dst = (uint4*)(hallT + (size_t)(100 + t) * 4096 + (4088 - s0));
                v0 = (uint4){a7, a6, a5, a4}; v1 = (uint4){a3, a2, a1, a0};
            }
            dst[0] = v0; dst[1] = v1;
        }

        float acc0 = 0.f, acc1 = 0.f, acc2 = 0.f, acc3 = 0.f, acc4 = 0.f, acc5 = 0.f, acc6 = 0.f;
        DOT_BLOCK(0, W0,  W1,  W2,  W3,  W4,  W5,  W6)
        DOT_BLOCK(4, W7,  W8,  W9,  W10, W11, W12, W13)
        DOT_BLOCK(8, W14, W15, W16, W17, W18, W19, W20)
        {
            u32 hb = hbase[12];
            acc0 = fdot2(W21.x, hb, acc0); acc1 = fdot2(W21.y, hb, acc1);
            acc2 = fdot2(W21.z, hb, acc2); acc3 = fdot2(W21.w, hb, acc3);
            acc4 = fdot2(W22.x, hb, acc4); acc5 = fdot2(W22.y, hb, acc5);
            acc6 = fdot2(W22.z, hb, acc6);
        }
        REDUCE(acc0) REDUCE(acc1) REDUCE(acc2) REDUCE(acc3) REDUCE(acc4) REDUCE(acc5) REDUCE(acc6)
        if (ks == 0) {
            gsh[r0]     = acc0; gsh[r0 + 1] = acc1; gsh[r0 + 2] = acc2;
            gsh[r0 + 3] = acc3; gsh[r0 + 4] = acc4; gsh[r0 + 5] = acc5;
            gsh[r0 + 6] = acc6;
        }
        __syncthreads();   // A: gsh ready, x loads + h stores drained (hidden)

        if (t < 200) {
            float gi = gsh[t] + xr0, gf = gsh[200 + t] + xr1;
            float gg = gsh[400 + t] + xr2, go = gsh[600 + t] + xr3;
            float is = sigf(gi), fs = sigf(gf), gt = tanhf_(gg), os = sigf(go);
            cst = fs * cst + is * gt;
            float hv = os * tanhf_(cst);
            float hq = __shfl_xor(hv, 1);
            if (!(t & 1)) {
                u32 pv = pack2(hv, hq);
                hsh[haddr] = pv;
                hstage[(s & 7) * 100 + (t >> 1)] = pv;
            }
        }
        __syncthreads();   // B: hsh/hstage ready for next step (lgkm-only, cheap)
    }
    // final batch (steps 4088..4095)
    if (t < 100) {
        u32 a0 = hstage[t],       a1 = hstage[100 + t], a2 = hstage[200 + t], a3 = hstage[300 + t];
        u32 a4 = hstage[400 + t], a5 = hstage[500 + t], a6 = hstage[600 + t], a7 = hstage[700 + t];
        uint4* dst;
        uint4 v0, v1;
        if (dir == 0) {
            dst = (uint4*)(hallT + (size_t)t * 4096 + 4088);
            v0 = (uint4){a0, a1, a2, a3}; v1 = (uint4){a4, a5, a6, a7};
        } else {
            dst = (uint4*)(hallT + (size_t)(100 + t) * 4096);
            v0 = (uint4){a7, a6, a5, a4}; v1 = (uint4){a3, a2, a1, a0};
        }
        dst[0] = v0; dst[1] = v1;
    }
}

// =============== K3: final linear, one block per sequence position ===============
__global__ __launch_bounds__(64) void k_linear(
    const u32* __restrict__ hallT, const u32* __restrict__ lwp,
    const float* __restrict__ lb, float* __restrict__ feats)
{
    int s = blockIdx.x, t = threadIdx.x;
    __shared__ __align__(16) u32 hc[200];
#pragma unroll
    for (int k = 0; k < 4; k++) {
        int u = t + 64 * k;
        if (u < 200) hc[u] = hallT[(size_t)u * 4096 + s];
    }
    __syncthreads();
    if (t < 50) {
        const uint4* wp = (const uint4*)(lwp + t * 200);
        const uint4* hp = (const uint4*)hc;
        float acc = lb[t];
#pragma unroll 10
        for (int c = 0; c < 50; c++) {
            uint4 wv = wp[c]; uint4 hv = hp[c];
            acc = fdot2(wv.x, hv.x, acc); acc = fdot2(wv.y, hv.y, acc);
            acc = fdot2(wv.z, hv.z, acc); acc = fdot2(wv.w, hv.w, acc);
        }
        feats[(size_t)s * 50 + t] = acc;
    }
}

// =============== K4: CRF forward (block0) + Viterbi (block1) + gold score (block2) ===============
__global__ __launch_bounds__(512) void k_crf(
    const float* __restrict__ feats, const float* __restrict__ trans,
    const int* __restrict__ tags, u8* __restrict__ bp, float* __restrict__ scal)
{
    __shared__ float tl[2500];
    __shared__ float al[2][64];
    __shared__ float red[512];
    int t = threadIdx.x;
    for (int i = t; i < 2500; i += 512) tl[i] = trans[i];
    __syncthreads();

    int role = blockIdx.x;
    if (role == 2) {        // gold score
        float loc = 0.f;
        for (int i = t; i < 4096; i += 512) {
            int prev = i ? tags[i - 1] : TSTART;
            int cur = tags[i];
            loc += tl[prev * 50 + cur] + feats[(size_t)i * 50 + cur];
        }
        red[t] = loc; __syncthreads();
        for (int w = 256; w > 0; w >>= 1) { if (t < w) red[t] += red[t + w]; __syncthreads(); }
        if (t == 0) scal[1] = red[0] + tl[tags[4095] * 50 + TEND];
        return;
    }

    int j = t >> 3, q = t & 7;
    bool jv = j < 50;
    float Tc[7];
#pragma unroll
    for (int r = 0; r < 7; r++) {
        int i = q + 8 * r;
        Tc[r] = (jv && i < 50) ? tl[i * 50 + j] : 0.f;
    }
    if (t < 64) al[0][t] = (t == TSTART) ? 0.f : NEGV;
    __syncthreads();

    int cur = 0;
    float fcur = 0.f;
    if (q == 0 && jv) fcur = feats[j];

    if (role == 0) {        // CRF forward (logsumexp)
        for (int s = 0; s < 4096; ++s) {
            float fnext = 0.f;
            if (s + 1 < 4096 && q == 0 && jv) fnext = feats[(size_t)(s + 1) * 50 + j];
            float v[7]; float m = -3.0e38f;
#pragma unroll
            for (int r = 0; r < 7; r++) {
                int i = q + 8 * r;
                float vv = (i < 50) ? al[cur][i] + Tc[r] : -3.0e38f;
                v[r] = vv; m = fmaxf(m, vv);
            }
            m = fmaxf(m, __shfl_xor(m, 1));
            m = fmaxf(m, __shfl_xor(m, 2));
            m = fmaxf(m, __shfl_xor(m, 4));
            float sum = 0.f;
#pragma unroll
            for (int r = 0; r < 7; r++) {
                int i = q + 8 * r;
                if (i < 50) sum += __expf(v[r] - m);
            }
            sum += __shfl_xor(sum, 1);
            sum += __shfl_xor(sum, 2);
            sum += __shfl_xor(sum, 4);
            if (q == 0 && jv) al[cur ^ 1][j] = fcur + m + __logf(sum);
            fcur = fnext; cur ^= 1;
            __syncthreads();
        }
        if (t == 0) {
            float m = -3.0e38f;
            for (int i = 0; i < 50; i++) m = fmaxf(m, al[cur][i] + tl[i * 50 + TEND]);
            float sm = 0.f;
            for (int i = 0; i < 50; i++) sm += __expf(al[cur][i] + tl[i * 50 + TEND] - m);
            scal[0] = m + __logf(sm);
        }
    } else {                // Viterbi
        for (int s = 0; s < 4096; ++s) {
            float fnext = 0.f;
            if (s + 1 < 4096 && q == 0 && jv) fnext = feats[(size_t)(s + 1) * 50 + j];
            float m = -3.0e38f; int mi = 63;
#pragma unroll
            for (int r = 0; r < 7; r++) {
                int i = q + 8 * r;
                float vv = (i < 50) ? al[cur][i] + Tc[r] : -3.0e38f;
                if (vv > m) { m = vv; mi = i; }
            }
#pragma unroll
            for (int k = 1; k < 8; k <<= 1) {
                float om = __shfl_xor(m, k); int oi = __shfl_xor(mi, k);
                if (om > m || (om == m && oi < mi)) { m = om; mi = oi; }
            }
            if (q == 0 && jv) {
                al[cur ^ 1][j] = m + fcur;
                bp[(size_t)s * 50 + j] = (u8)mi;
            }
            fcur = fnext; cur ^= 1;
            __syncthreads();
        }
        if (t == 0) {
            float best = -3.0e38f; int bi = 0;
            for (int i = 0; i < 50; i++) {
                float f = al[cur][i] + tl[i * 50 + TEND];
                if (f > best) { best = f; bi = i; }
            }
            ((int*)scal)[2] = bi;
        }
    }
}

// =============== K5: per-chunk composed backtrace maps ===============
__global__ __launch_bounds__(64) void k_maps(const u8* __restrict__ bp, u8* __restrict__ fmap)
{
    __shared__ __align__(4) u8 bpl[3200];
    int c = blockIdx.x, t = threadIdx.x;
    const u32* src = (const u32*)(bp + (size_t)c * 3200);
    u32* dst = (u32*)bpl;
    for (int i = t; i < 800; i += 64) dst[i] = src[i];
    __syncthreads();
    if (t < 50) {
        int y = t;
        for (int k = 63; k >= 0; --k) y = bpl[k * 50 + y];
        fmap[c * 50 + t] = (u8)y;
    }
}

// =============== K6: boundary chase + loss ===============
__global__ __launch_bounds__(64) void k_chase(const u8* __restrict__ fmap, const float* __restrict__ scal,
                                              u8* __restrict__ btag, float* __restrict__ dout)
{
    __shared__ __align__(4) u8 fl[3200];
    int t = threadIdx.x;
    for (int i = t; i < 800; i += 64) ((u32*)fl)[i] = ((const u32*)fmap)[i];
    __syncthreads();
    if (t == 0) {
        int b = ((const int*)scal)[2];
        btag[63] = (u8)b;
        for (int c = 63; c >= 1; --c) { b = fl[c * 50 + b]; btag[c - 1] = (u8)b; }
        dout[4096] = scal[0] - scal[1];
    }
}

// =============== K7: per-chunk path replay ===============
__global__ __launch_bounds__(64) void k_replay(const u8* __restrict__ bp, const u8* __restrict__ btag,
                                               float* __restrict__ dout)
{
    __shared__ __align__(4) u8 bpl[3200];
    int c = blockIdx.x, t = threadIdx.x;
    for (int i = t; i < 800; i += 64) ((u32*)bpl)[i] = ((const u32*)(bp + (size_t)c * 3200))[i];
    __syncthreads();
    if (t == 0) {
        int y = btag[c];
        dout[c * 64 + 63] = (float)y;
        for (int k = 62; k >= 0; --k) {
            y = bpl[(k + 1) * 50 + y];
            dout[c * 64 + k] = (float)y;
        }
    }
}

extern "C" void kernel_launch(void* const* d_in, const int* in_sizes, int n_in,
                              void* d_out, int out_size, void* d_ws, size_t ws_size,
                              hipStream_t stream)
{
    const int*   ids   = (const int*)d_in[0];
    const int*   tags  = (const int*)d_in[1];
    const float* emb   = (const float*)d_in[2];
    const float* wihf  = (const float*)d_in[3];
    const float* whhf  = (const float*)d_in[4];
    const float* bihf  = (const float*)d_in[5];
    const float* bhhf  = (const float*)d_in[6];
    const float* wihb  = (const float*)d_in[7];
    const float* whhb  = (const float*)d_in[8];
    const float* bihb  = (const float*)d_in[9];
    const float* bhhb  = (const float*)d_in[10];
    const float* lw    = (const float*)d_in[11];
    const float* lb    = (const float*)d_in[12];
    const float* trans = (const float*)d_in[13];
    const float* h0    = (const float*)d_in[14];
    const float* c0    = (const float*)d_in[15];
    float* dout = (float*)d_out;

    char* w = (char*)d_ws;
    u32*   xg    = (u32*)(w + O_XG);
    u32*   wif16 = (u32*)(w + O_WIHF);
    u32*   wib16 = (u32*)(w + O_WIHB);
    u32*   whf16 = (u32*)(w + O_WHHF);
    u32*   whb16 = (u32*)(w + O_WHHB);
    float* bsf   = (float*)(w + O_BSF);
    float* bsb   = (float*)(w + O_BSB);
    u32*   lwp   = (u32*)(w + O_LWP);
    float* xf    = (float*)(w + O_XF);
    float* xb    = (float*)(w + O_XB);
    u32*   hallT = (u32*)(w + O_HT);
    float* feats = (float*)(w + O_FEATS);
    u8*    bp    = (u8*)(w + O_BP);
    u8*    fmap  = (u8*)(w + O_FMAP);
    u8*    btag  = (u8*)(w + O_BTAG);
    float* scal  = (float*)(w + O_SCAL);

    k_prep<<<6478, 256, 0, stream>>>(ids, emb, wihf, wihb, whhf, whhb,
                                     bihf, bhhf, bihb, bhhb, lw,
                                     xg, wif16, wib16, whf16, whb16, lwp, bsf, bsb);
    k_gemm<<<dim3(16, 7, 2), 256, 0, stream>>>(xg, wif16, wib16, bsf, bsb, xf, xb);
    k_lstm<<<2, 1024, 0, stream>>>(whf16, whb16, xf, xb, h0, c0, hallT);
    k_linear<<<4096, 64, 0, stream>>>(hallT, lwp, lb, feats);
    k_crf<<<3, 512, 0, stream>>>(feats, trans, tags, bp, scal);
    k_maps<<<64, 64, 0, stream>>>(bp, fmap);
    k_chase<<<1, 64, 0, stream>>>(fmap, scal, btag, dout);
    k_replay<<<64, 64, 0, stream>>>(bp, btag, dout);
}

// Round 8
// 7611.980 us; speedup vs baseline: 1.3947x; 1.3947x over previous
//
#include <hip/hip_runtime.h>

typedef unsigned int u32;
typedef unsigned char u8;

#define TSTART 48
#define TEND   49
#define NEGV  -10000.0f

// ---- workspace byte offsets ----
#define O_XG     0ull            // 4096*256*4   = 4,194,304 (x gathered f16x2, k 250->256)
#define O_WIHF   4194304ull      // 800*256*4    = 819,200
#define O_WIHB   5013504ull      // 819,200
#define O_WHHF   5832704ull      // 512 chunks * 176 dwords * 4 = 360,448 (per-thread packed)
#define O_WHHB   6193152ull      // 360,448
#define O_BSF    6553600ull      // 3,200
#define O_BSB    6556800ull      // 3,200
#define O_LWP    6560000ull      // 50*200*4 = 40,000 (linear_w packed f16 pairs)
#define O_XF     6600000ull      // 4096*800*4 = 13,107,200
#define O_XB     19707200ull     // 13,107,200
#define O_HT     32814400ull     // 200 rows * 4096 * 4 = 3,276,800 (h pairs f16x2, [pair][seq])
#define O_FEATS  36091200ull     // 4096*50*4 = 819,200
#define O_BP     36910400ull     // 204,800
#define O_FMAP   37115200ull     // 3,200
#define O_BTAG   37118400ull     // 256
#define O_SCAL   37118656ull     // 64

typedef _Float16 h2 __attribute__((ext_vector_type(2)));

__device__ __forceinline__ float fdot2(u32 a, u32 b, float c) {
#if defined(__HIP_DEVICE_COMPILE__) && __has_builtin(__builtin_amdgcn_fdot2)
    return __builtin_amdgcn_fdot2(__builtin_bit_cast(h2, a), __builtin_bit_cast(h2, b), c, false);
#else
    float d;
    asm("v_dot2_f32_f16 %0, %1, %2, %3" : "=v"(d) : "v"(a), "v"(b), "v"(c));
    return d;
#endif
}

__device__ __forceinline__ u32 pack2(float a, float b) {
    u32 lo = __builtin_bit_cast(unsigned short, (_Float16)a);
    u32 hi = __builtin_bit_cast(unsigned short, (_Float16)b);
    return lo | (hi << 16);
}

__device__ __forceinline__ float sigf(float x) { return 1.f / (1.f + __expf(-x)); }
__device__ __forceinline__ float tanhf_(float x) { return 2.f / (1.f + __expf(-2.f * x)) - 1.f; }

// element ranges in k_prep's flat index space (dword elements)
#define PA_END   90112      // whf packed (512 chunks * 176)
#define PB_END   180224     // whb packed
#define PC_END   385024     // wihf
#define PD_END   589824     // wihb
#define PE_END   1638400    // xg
#define PF_END   1648400    // lwpack
#define PG_END   1649200    // bsf
#define PH_END   1650000    // bsb

// whh per-thread packed layout: chunk = thread id t in [0,512) = rgrp*4+ks.
// chunk holds 176 dwords: off<168: q=off>>2,e=off&3,c4=q/7,m=q%7 -> row=rgrp*7+m, kd=ks*25+c4*4+e
//              off in [168,175): m=off-168, kd=ks*25+24 ; off=175: zero pad
__global__ __launch_bounds__(256) void k_prep(
    const int* __restrict__ ids, const float* __restrict__ emb,
    const float* __restrict__ wihf, const float* __restrict__ wihb,
    const float* __restrict__ whhf, const float* __restrict__ whhb,
    const float* __restrict__ bihf, const float* __restrict__ bhhf,
    const float* __restrict__ bihb, const float* __restrict__ bhhb,
    const float* __restrict__ lw,
    u32* __restrict__ xg, u32* __restrict__ wif16, u32* __restrict__ wib16,
    u32* __restrict__ whf16, u32* __restrict__ whb16, u32* __restrict__ lwp,
    float* __restrict__ bsf, float* __restrict__ bsb)
{
    int idx = blockIdx.x * 256 + threadIdx.x;
    if (idx < PB_END) {                               // packed whh (both dirs)
        int dirb = (idx >= PA_END);
        int i = idx - (dirb ? PA_END : 0);
        const float* whh = dirb ? whhb : whhf;
        u32* dst = dirb ? whb16 : whf16;
        int chunk = i / 176, off = i % 176;
        int rgrp = chunk >> 2, ks = chunk & 3;
        u32 v = 0;
        if (off < 175) {
            int m, kd;
            if (off < 168) { int q = off >> 2, e = off & 3; kd = ks * 25 + (q / 7) * 4 + e; m = q % 7; }
            else           { m = off - 168; kd = ks * 25 + 24; }
            int row = rgrp * 7 + m;
            if (row < 800) v = pack2(whh[row * 200 + 2 * kd], whh[row * 200 + 2 * kd + 1]);
        }
        dst[i] = v;
    } else if (idx < PD_END) {                        // wih: [800][256]
        int dirb = (idx >= PC_END);
        int i = idx - (dirb ? PC_END : PB_END);
        const float* wih = dirb ? wihb : wihf;
        u32* dst = dirb ? wib16 : wif16;
        int r = i >> 8, d = i & 255;
        dst[i] = (d < 250) ? pack2(wih[r * 500 + 2 * d], wih[r * 500 + 2 * d + 1]) : 0u;
    } else if (idx < PE_END) {                        // xg: [4096][256]
        int i = idx - PD_END; int s = i >> 8, d = i & 255;
        long id = ids[s];
        xg[i] = (d < 250) ? pack2(emb[id * 500 + 2 * d], emb[id * 500 + 2 * d + 1]) : 0u;
    } else if (idx < PF_END) {                        // lwpack [50][200]
        int i = idx - PE_END; int tag = i / 200, u = i % 200;
        lwp[i] = pack2(lw[tag * 400 + 2 * u], lw[tag * 400 + 2 * u + 1]);
    } else if (idx < PG_END) {
        int j = idx - PF_END; bsf[j] = bihf[j] + bhhf[j];
    } else if (idx < PH_END) {
        int j = idx - PG_END; bsb[j] = bihb[j] + bhhb[j];
    }
}

// =============== K1: input GEMM  xp[s][j] = dot(x[s or rev], w_ih[j]) + bias ===============
__global__ __launch_bounds__(256, 2) void k_gemm(
    const u32* __restrict__ xg, const u32* __restrict__ wf, const u32* __restrict__ wb,
    const float* __restrict__ bsf, const float* __restrict__ bsb,
    float* __restrict__ xf, float* __restrict__ xb)
{
    int z = blockIdx.z;
    const u32* W = z ? wb : wf;
    const float* bs = z ? bsb : bsf;
    float* out = z ? xb : xf;
    int m0 = blockIdx.x * 256, n0 = blockIdx.y * 128;
    int t = threadIdx.x;

    __shared__ u32 As[16][256];
    __shared__ u32 Bs[16][128];

    float acc[16][8];
#pragma unroll
    for (int m = 0; m < 16; m++)
#pragma unroll
        for (int n = 0; n < 8; n++) acc[m][n] = 0.f;

    int arow = m0 + t; if (z) arow = 4095 - arow;
    const u32* aptr = xg + (size_t)arow * 256;
    int bj = n0 + (t >> 1);
    int ko = (t & 1) * 8;
    const u32* bptr = W + (size_t)bj * 256 + ko;

    int ry = t >> 4, cx = t & 15;

    for (int kc = 0; kc < 16; ++kc) {
        int kd = kc * 16;
        uint4 a0 = *(const uint4*)(aptr + kd);
        uint4 a1 = *(const uint4*)(aptr + kd + 4);
        uint4 a2 = *(const uint4*)(aptr + kd + 8);
        uint4 a3 = *(const uint4*)(aptr + kd + 12);
        uint4 bv0 = {0,0,0,0}, bv1 = {0,0,0,0};
        if (bj < 800) { bv0 = *(const uint4*)(bptr + kd); bv1 = *(const uint4*)(bptr + kd + 4); }
        __syncthreads();
        u32 ad[16] = {a0.x,a0.y,a0.z,a0.w, a1.x,a1.y,a1.z,a1.w,
                      a2.x,a2.y,a2.z,a2.w, a3.x,a3.y,a3.z,a3.w};
#pragma unroll
        for (int i = 0; i < 16; i++) As[i][t] = ad[i];
        u32 bd[8] = {bv0.x,bv0.y,bv0.z,bv0.w, bv1.x,bv1.y,bv1.z,bv1.w};
#pragma unroll
        for (int i = 0; i < 8; i++) Bs[ko + i][t >> 1] = bd[i];
        __syncthreads();
#pragma unroll
        for (int d = 0; d < 16; ++d) {
            const u32* ar = &As[d][ry * 16];
            uint4 x0 = *(const uint4*)(ar);
            uint4 x1 = *(const uint4*)(ar + 4);
            uint4 x2 = *(const uint4*)(ar + 8);
            uint4 x3 = *(const uint4*)(ar + 12);
            const u32* br = &Bs[d][cx * 8];
            uint4 y0 = *(const uint4*)(br);
            uint4 y1 = *(const uint4*)(br + 4);
            u32 am[16] = {x0.x,x0.y,x0.z,x0.w, x1.x,x1.y,x1.z,x1.w,
                          x2.x,x2.y,x2.z,x2.w, x3.x,x3.y,x3.z,x3.w};
            u32 bn[8] = {y0.x,y0.y,y0.z,y0.w, y1.x,y1.y,y1.z,y1.w};
#pragma unroll
            for (int m = 0; m < 16; m++)
#pragma unroll
                for (int n = 0; n < 8; n++)
                    acc[m][n] = fdot2(am[m], bn[n], acc[m][n]);
        }
    }
    int col = n0 + cx * 8;
    if (col < 800) {
        float4 bi0 = *(const float4*)(bs + col);
        float4 bi1 = *(const float4*)(bs + col + 4);
#pragma unroll
        for (int m = 0; m < 16; m++) {
            size_t ro = (size_t)(m0 + ry * 16 + m) * 800 + col;
            float4 o0 = {acc[m][0]+bi0.x, acc[m][1]+bi0.y, acc[m][2]+bi0.z, acc[m][3]+bi0.w};
            float4 o1 = {acc[m][4]+bi1.x, acc[m][5]+bi1.y, acc[m][6]+bi1.z, acc[m][7]+bi1.w};
            *(float4*)(out + ro) = o0;
            *(float4*)(out + ro + 4) = o1;
        }
    }
}

// =============== K2: LSTM recurrence. 512 threads: t = rgrp*4+ks ===============
// rgrp in [0,128): rows rgrp*7..+6 (padded 896); ks in [0,4): k-dwords ks*25..+24 of 100.
// 175 weight dwords per thread in NAMED registers.
// ATTRIBUTE EXPERIMENT (round 8): rounds 1-7 showed the VGPR budget = "2 workgroups/CU
// from block size alone" (256t->256, 512t->128, 1024t->64), with launch_bounds present.
// launch_bounds and amdgpu_waves_per_eu both lower to amdgpu-waves-per-eu and conflict.
// Here: NO launch_bounds; raw amdgpu_flat_work_group_size(512,512) +
// amdgpu_waves_per_eu(2,2) -> if honored, 2 waves/SIMD target -> 256-VGPR budget ->
// the full 175-dw weight set is register-resident, no sinking, no spill.

#define LOAD_WROW(c) \
    uint4 W##c##0 = p[(c)*7+0], W##c##1 = p[(c)*7+1], W##c##2 = p[(c)*7+2], \
          W##c##3 = p[(c)*7+3], W##c##4 = p[(c)*7+4], W##c##5 = p[(c)*7+5], \
          W##c##6 = p[(c)*7+6];

#define DOTQ(Wv, A) \
    A = fdot2(Wv.x, hb.x, A); A = fdot2(Wv.y, hb.y, A); \
    A = fdot2(Wv.z, hb.z, A); A = fdot2(Wv.w, hb.w, A);

#define DOT_BLOCK(c) { \
    uint4 hb = *(const uint4*)(hbase + (c)*4); \
    DOTQ(W##c##0, acc0) DOTQ(W##c##1, acc1) DOTQ(W##c##2, acc2) DOTQ(W##c##3, acc3) \
    DOTQ(W##c##4, acc4) DOTQ(W##c##5, acc5) DOTQ(W##c##6, acc6) }

#define REDUCE(A) A += __shfl_xor(A, 1); A += __shfl_xor(A, 2);

__global__ __attribute__((amdgpu_flat_work_group_size(512, 512), amdgpu_waves_per_eu(2, 2)))
void k_lstm(
    const u32* __restrict__ whf, const u32* __restrict__ whb,
    const float* __restrict__ xf, const float* __restrict__ xb,
    const float* __restrict__ h0, const float* __restrict__ c0,
    u32* __restrict__ hallT)
{
    int dir = blockIdx.x, t = threadIdx.x;
    const u32* Wh = dir ? whb : whf;
    const float* xp = dir ? xb : xf;
    int ks = t & 3, rgrp = t >> 2, r0 = rgrp * 7;

    const uint4* p = (const uint4*)(Wh + (size_t)t * 176);
    LOAD_WROW(0) LOAD_WROW(1) LOAD_WROW(2) LOAD_WROW(3) LOAD_WROW(4) LOAD_WROW(5)
    const u32* p1 = Wh + (size_t)t * 176 + 168;
    u32 U0 = p1[0], U1 = p1[1], U2 = p1[2], U3 = p1[3], U4 = p1[4], U5 = p1[5], U6 = p1[6];

    __shared__ __align__(16) u32 hsh[112];   // 4 slices * 28 dwords (25 used)
    __shared__ float gsh[800];
    __shared__ u32 hstage[800];              // [8 steps][100 pairs]

    if (t < 112) hsh[t] = 0u;
    __syncthreads();

    float cst = 0.f;
    int haddr = 0;
    if (t < 200) {
        cst = c0[dir * 200 + t];
        int u = t >> 1;
        haddr = (u / 25) * 28 + (u % 25);
        if (!(t & 1)) hsh[haddr] = pack2(h0[dir * 200 + t], h0[dir * 200 + t + 1]);
    }
    __syncthreads();

    const u32* hbase = hsh + ks * 28;

    for (int s = 0; s < 4096; ++s) {
        // x loads for THIS step issued early: latency hides under dot work,
        // so barrier A's vmcnt drain is free.
        float xr0 = 0.f, xr1 = 0.f, xr2 = 0.f, xr3 = 0.f;
        if (t < 200) {
            size_t xo = (size_t)s * 800 + t;
            xr0 = xp[xo]; xr1 = xp[xo + 200]; xr2 = xp[xo + 400]; xr3 = xp[xo + 600];
        }
        // flush previous 8-step h batch from LDS stage (store-ack drains with x loads)
        if ((s & 7) == 0 && s && t < 100) {
            int s0 = s - 8;
            u32 a0 = hstage[t],       a1 = hstage[100 + t], a2 = hstage[200 + t], a3 = hstage[300 + t];
            u32 a4 = hstage[400 + t], a5 = hstage[500 + t], a6 = hstage[600 + t], a7 = hstage[700 + t];
            uint4* dst;
            uint4 v0, v1;
            if (dir == 0) {
                dst = (uint4*)(hallT + (size_t)t * 4096 + s0);
                v0 = (uint4){a0, a1, a2, a3}; v1 = (uint4){a4, a5, a6, a7};
            } else {
                dst = (uint4*)(hallT + (size_t)(100 + t) * 4096 + (4088 - s0));
                v0 = (uint4){a7, a6, a5, a4}; v1 = (uint4){a3, a2, a1, a0};
            }
            dst[0] = v0; dst[1] = v1;
        }

        float acc0 = 0.f, acc1 = 0.f, acc2 = 0.f, acc3 = 0.f, acc4 = 0.f, acc5 = 0.f, acc6 = 0.f;
        DOT_BLOCK(0) DOT_BLOCK(1) DOT_BLOCK(2) DOT_BLOCK(3) DOT_BLOCK(4) DOT_BLOCK(5)
        {
            u32 hb1 = hbase[24];
            acc0 = fdot2(U0, hb1, acc0); acc1 = fdot2(U1, hb1, acc1);
            acc2 = fdot2(U2, hb1, acc2); acc3 = fdot2(U3, hb1, acc3);
            acc4 = fdot2(U4, hb1, acc4); acc5 = fdot2(U5, hb1, acc5);
            acc6 = fdot2(U6, hb1, acc6);
        }
        REDUCE(acc0) REDUCE(acc1) REDUCE(acc2) REDUCE(acc3) REDUCE(acc4) REDUCE(acc5) REDUCE(acc6)
        if (ks == 0 && r0 < 800) {
            gsh[r0] = acc0;
            if (r0 + 1 < 800) gsh[r0 + 1] = acc1;
            if (r0 + 2 < 800) gsh[r0 + 2] = acc2;
            if (r0 + 3 < 800) gsh[r0 + 3] = acc3;
            if (r0 + 4 < 800) gsh[r0 + 4] = acc4;
            if (r0 + 5 < 800) gsh[r0 + 5] = acc5;
            if (r0 + 6 < 800) gsh[r0 + 6] = acc6;
        }
        __syncthreads();   // A: gsh ready, x loads + h stores drained (hidden)

        if (t < 200) {
            float gi = gsh[t] + xr0, gf = gsh[200 + t] + xr1;
            float gg = gsh[400 + t] + xr2, go = gsh[600 + t] + xr3;
            float is = sigf(gi), fs = sigf(gf), gt = tanhf_(gg), os = sigf(go);
            cst = fs * cst + is * gt;
            float hv = os * tanhf_(cst);
            float hq = __shfl_xor(hv, 1);
            if (!(t & 1)) {
                u32 pv = pack2(hv, hq);
                hsh[haddr] = pv;
                hstage[(s & 7) * 100 + (t >> 1)] = pv;
            }
        }
        __syncthreads();   // B: hsh/hstage ready for next step (lgkm-only, cheap)
    }
    // final batch (steps 4088..4095)
    if (t < 100) {
        u32 a0 = hstage[t],       a1 = hstage[100 + t], a2 = hstage[200 + t], a3 = hstage[300 + t];
        u32 a4 = hstage[400 + t], a5 = hstage[500 + t], a6 = hstage[600 + t], a7 = hstage[700 + t];
        uint4* dst;
        uint4 v0, v1;
        if (dir == 0) {
            dst = (uint4*)(hallT + (size_t)t * 4096 + 4088);
            v0 = (uint4){a0, a1, a2, a3}; v1 = (uint4){a4, a5, a6, a7};
        } else {
            dst = (uint4*)(hallT + (size_t)(100 + t) * 4096);
            v0 = (uint4){a7, a6, a5, a4}; v1 = (uint4){a3, a2, a1, a0};
        }
        dst[0] = v0; dst[1] = v1;
    }
}

// =============== K3: final linear, one block per sequence position ===============
__global__ __launch_bounds__(64) void k_linear(
    const u32* __restrict__ hallT, const u32* __restrict__ lwp,
    const float* __restrict__ lb, float* __restrict__ feats)
{
    int s = blockIdx.x, t = threadIdx.x;
    __shared__ __align__(16) u32 hc[200];
#pragma unroll
    for (int k = 0; k < 4; k++) {
        int u = t + 64 * k;
        if (u < 200) hc[u] = hallT[(size_t)u * 4096 + s];
    }
    __syncthreads();
    if (t < 50) {
        const uint4* wp = (const uint4*)(lwp + t * 200);
        const uint4* hp = (const uint4*)hc;
        float acc = lb[t];
#pragma unroll 10
        for (int c = 0; c < 50; c++) {
            uint4 wv = wp[c]; uint4 hv = hp[c];
            acc = fdot2(wv.x, hv.x, acc); acc = fdot2(wv.y, hv.y, acc);
            acc = fdot2(wv.z, hv.z, acc); acc = fdot2(wv.w, hv.w, acc);
        }
        feats[(size_t)s * 50 + t] = acc;
    }
}

// =============== K4: CRF forward (block0) + Viterbi (block1) + gold score (block2) ===============
__global__ __launch_bounds__(512) void k_crf(
    const float* __restrict__ feats, const float* __restrict__ trans,
    const int* __restrict__ tags, u8* __restrict__ bp, float* __restrict__ scal)
{
    __shared__ float tl[2500];
    __shared__ float al[2][64];
    __shared__ float red[512];
    int t = threadIdx.x;
    for (int i = t; i < 2500; i += 512) tl[i] = trans[i];
    __syncthreads();

    int role = blockIdx.x;
    if (role == 2) {        // gold score
        float loc = 0.f;
        for (int i = t; i < 4096; i += 512) {
            int prev = i ? tags[i - 1] : TSTART;
            int cur = tags[i];
            loc += tl[prev * 50 + cur] + feats[(size_t)i * 50 + cur];
        }
        red[t] = loc; __syncthreads();
        for (int w = 256; w > 0; w >>= 1) { if (t < w) red[t] += red[t + w]; __syncthreads(); }
        if (t == 0) scal[1] = red[0] + tl[tags[4095] * 50 + TEND];
        return;
    }

    int j = t >> 3, q = t & 7;
    bool jv = j < 50;
    float Tc[7];
#pragma unroll
    for (int r = 0; r < 7; r++) {
        int i = q + 8 * r;
        Tc[r] = (jv && i < 50) ? tl[i * 50 + j] : 0.f;
    }
    if (t < 64) al[0][t] = (t == TSTART) ? 0.f : NEGV;
    __syncthreads();

    int cur = 0;
    float fcur = 0.f;
    if (q == 0 && jv) fcur = feats[j];

    if (role == 0) {        // CRF forward (logsumexp)
        for (int s = 0; s < 4096; ++s) {
            float fnext = 0.f;
            if (s + 1 < 4096 && q == 0 && jv) fnext = feats[(size_t)(s + 1) * 50 + j];
            float v[7]; float m = -3.0e38f;
#pragma unroll
            for (int r = 0; r < 7; r++) {
                int i = q + 8 * r;
                float vv = (i < 50) ? al[cur][i] + Tc[r] : -3.0e38f;
                v[r] = vv; m = fmaxf(m, vv);
            }
            m = fmaxf(m, __shfl_xor(m, 1));
            m = fmaxf(m, __shfl_xor(m, 2));
            m = fmaxf(m, __shfl_xor(m, 4));
            float sum = 0.f;
#pragma unroll
            for (int r = 0; r < 7; r++) {
                int i = q + 8 * r;
                if (i < 50) sum += __expf(v[r] - m);
            }
            sum += __shfl_xor(sum, 1);
            sum += __shfl_xor(sum, 2);
            sum += __shfl_xor(sum, 4);
            if (q == 0 && jv) al[cur ^ 1][j] = fcur + m + __logf(sum);
            fcur = fnext; cur ^= 1;
            __syncthreads();
        }
        if (t == 0) {
            float m = -3.0e38f;
            for (int i = 0; i < 50; i++) m = fmaxf(m, al[cur][i] + tl[i * 50 + TEND]);
            float sm = 0.f;
            for (int i = 0; i < 50; i++) sm += __expf(al[cur][i] + tl[i * 50 + TEND] - m);
            scal[0] = m + __logf(sm);
        }
    } else {                // Viterbi
        for (int s = 0; s < 4096; ++s) {
            float fnext = 0.f;
            if (s + 1 < 4096 && q == 0 && jv) fnext = feats[(size_t)(s + 1) * 50 + j];
            float m = -3.0e38f; int mi = 63;
#pragma unroll
            for (int r = 0; r < 7; r++) {
                int i = q + 8 * r;
                float vv = (i < 50) ? al[cur][i] + Tc[r] : -3.0e38f;
                if (vv > m) { m = vv; mi = i; }
            }
#pragma unroll
            for (int k = 1; k < 8; k <<= 1) {
                float om = __shfl_xor(m, k); int oi = __shfl_xor(mi, k);
                if (om > m || (om == m && oi < mi)) { m = om; mi = oi; }
            }
            if (q == 0 && jv) {
                al[cur ^ 1][j] = m + fcur;
                bp[(size_t)s * 50 + j] = (u8)mi;
            }
            fcur = fnext; cur ^= 1;
            __syncthreads();
        }
        if (t == 0) {
            float best = -3.0e38f; int bi = 0;
            for (int i = 0; i < 50; i++) {
                float f = al[cur][i] + tl[i * 50 + TEND];
                if (f > best) { best = f; bi = i; }
            }
            ((int*)scal)[2] = bi;
        }
    }
}

// =============== K5: per-chunk composed backtrace maps ===============
__global__ __launch_bounds__(64) void k_maps(const u8* __restrict__ bp, u8* __restrict__ fmap)
{
    __shared__ __align__(4) u8 bpl[3200];
    int c = blockIdx.x, t = threadIdx.x;
    const u32* src = (const u32*)(bp + (size_t)c * 3200);
    u32* dst = (u32*)bpl;
    for (int i = t; i < 800; i += 64) dst[i] = src[i];
    __syncthreads();
    if (t < 50) {
        int y = t;
        for (int k = 63; k >= 0; --k) y = bpl[k * 50 + y];
        fmap[c * 50 + t] = (u8)y;
    }
}

// =============== K6: boundary chase + loss ===============
__global__ __launch_bounds__(64) void k_chase(const u8* __restrict__ fmap, const float* __restrict__ scal,
                                              u8* __restrict__ btag, float* __restrict__ dout)
{
    __shared__ __align__(4) u8 fl[3200];
    int t = threadIdx.x;
    for (int i = t; i < 800; i += 64) ((u32*)fl)[i] = ((const u32*)fmap)[i];
    __syncthreads();
    if (t == 0) {
        int b = ((const int*)scal)[2];
        btag[63] = (u8)b;
        for (int c = 63; c >= 1; --c) { b = fl[c * 50 + b]; btag[c - 1] = (u8)b; }
        dout[4096] = scal[0] - scal[1];
    }
}

// =============== K7: per-chunk path replay ===============
__global__ __launch_bounds__(64) void k_replay(const u8* __restrict__ bp, const u8* __restrict__ btag,
                                               float* __restrict__ dout)
{
    __shared__ __align__(4) u8 bpl[3200];
    int c = blockIdx.x, t = threadIdx.x;
    for (int i = t; i < 800; i += 64) ((u32*)bpl)[i] = ((const u32*)(bp + (size_t)c * 3200))[i];
    __syncthreads();
    if (t == 0) {
        int y = btag[c];
        dout[c * 64 + 63] = (float)y;
        for (int k = 62; k >= 0; --k) {
            y = bpl[(k + 1) * 50 + y];
            dout[c * 64 + k] = (float)y;
        }
    }
}

extern "C" void kernel_launch(void* const* d_in, const int* in_sizes, int n_in,
                              void* d_out, int out_size, void* d_ws, size_t ws_size,
                              hipStream_t stream)
{
    const int*   ids   = (const int*)d_in[0];
    const int*   tags  = (const int*)d_in[1];
    const float* emb   = (const float*)d_in[2];
    const float* wihf  = (const float*)d_in[3];
    const float* whhf  = (const float*)d_in[4];
    const float* bihf  = (const float*)d_in[5];
    const float* bhhf  = (const float*)d_in[6];
    const float* wihb  = (const float*)d_in[7];
    const float* whhb  = (const float*)d_in[8];
    const float* bihb  = (const float*)d_in[9];
    const float* bhhb  = (const float*)d_in[10];
    const float* lw    = (const float*)d_in[11];
    const float* lb    = (const float*)d_in[12];
    const float* trans = (const float*)d_in[13];
    const float* h0    = (const float*)d_in[14];
    const float* c0    = (const float*)d_in[15];
    float* dout = (float*)d_out;

    char* w = (char*)d_ws;
    u32*   xg    = (u32*)(w + O_XG);
    u32*   wif16 = (u32*)(w + O_WIHF);
    u32*   wib16 = (u32*)(w + O_WIHB);
    u32*   whf16 = (u32*)(w + O_WHHF);
    u32*   whb16 = (u32*)(w + O_WHHB);
    float* bsf   = (float*)(w + O_BSF);
    float* bsb   = (float*)(w + O_BSB);
    u32*   lwp   = (u32*)(w + O_LWP);
    float* xf    = (float*)(w + O_XF);
    float* xb    = (float*)(w + O_XB);
    u32*   hallT = (u32*)(w + O_HT);
    float* feats = (float*)(w + O_FEATS);
    u8*    bp    = (u8*)(w + O_BP);
    u8*    fmap  = (u8*)(w + O_FMAP);
    u8*    btag  = (u8*)(w + O_BTAG);
    float* scal  = (float*)(w + O_SCAL);

    k_prep<<<6446, 256, 0, stream>>>(ids, emb, wihf, wihb, whhf, whhb,
                                     bihf, bhhf, bihb, bhhb, lw,
                                     xg, wif16, wib16, whf16, whb16, lwp, bsf, bsb);
    k_gemm<<<dim3(16, 7, 2), 256, 0, stream>>>(xg, wif16, wib16, bsf, bsb, xf, xb);
    k_lstm<<<2, 512, 0, stream>>>(whf16, whb16, xf, xb, h0, c0, hallT);
    k_linear<<<4096, 64, 0, stream>>>(hallT, lwp, lb, feats);
    k_crf<<<3, 512, 0, stream>>>(feats, trans, tags, bp, scal);
    k_maps<<<64, 64, 0, stream>>>(bp, fmap);
    k_chase<<<1, 64, 0, stream>>>(fmap, scal, btag, dout);
    k_replay<<<64, 64, 0, stream>>>(bp, btag, dout);
}